// Round 16
// baseline (126.803 us; speedup 1.0000x reference)
//
#include <hip/hip_runtime.h>
#include <math.h>

// B=128, NU=32, NT=64, H=128, OUT_F=16, N_U=4096, N_A=8192
// Per-batch-local GNN. R16 = R15 restructured to QUARTER-BATCH blocks for
// 2-blocks/CU co-residency: 512 blocks x 512 threads (8 waves, n-split 8),
// __launch_bounds__(512,4) -> 2 blocks/CU, 4 waves/SIMD.
//   Rationale: R14 measured +2x per-CU work -> only +12% time => stage chain
//   is latency/barrier-bound. Independent co-resident blocks let one block's
//   compute fill the other's barrier/drain stalls (same-barrier waves can't).
//   Block (b, qt) owns 8 hu + 16 ha rows. ha stages MT=1 exact 16-row tiles;
//   hu stages run 16-row tiles with 8 valid rows: MFMA C-col m depends only
//   on X-row m, so stale rows 8-15 are discarded by masking store + colsum
//   (l15 < VALID). Colsums 4-way: own LDS partial + sc1 global partial;
//   psync4 waits on 3 same-XCD partners (blk +- 128*i, 128%8==0).
//   Packed bf16 A-frag weights from prep kernel (also zeroes flags),
//   prefetched one stage ahead. Vectorized final normalize (R15).
// Workspace: 64KB flags + 1MB partials + 416KB packed weights.
// (R19 == R16 resubmitted a third time: rounds 13-15 hit
//  GPUAcquisitionTimeout, never ran. Last verified state: R15 @ 120.76 us.)

using frag  = __attribute__((ext_vector_type(8))) short;   // 8 x bf16
using f32x4 = __attribute__((ext_vector_type(4))) float;

#define LDST 136
#define SCOPE_AGT __HIP_MEMORY_SCOPE_AGENT

__device__ __forceinline__ float  bf2f(ushort u) { return __uint_as_float(((unsigned)u) << 16); }
__device__ __forceinline__ ushort f2bf(float f) {
    unsigned u = __float_as_uint(f);
    u += 0x7fff + ((u >> 16) & 1);            // RNE
    return (ushort)(u >> 16);
}
__device__ __forceinline__ unsigned cvtpk(float lo, float hi) {   // [hi:lo] bf16 pair, RNE
    unsigned r;
    asm("v_cvt_pk_bf16_f32 %0, %1, %2" : "=v"(r) : "v"(lo), "v"(hi));
    return r;
}
__device__ __forceinline__ void gst16_sc(void* p, f32x4 v) {   // write-through to MALL
    asm volatile("global_store_dwordx4 %0, %1, off sc1" :: "v"(p), "v"(v) : "memory");
}

struct GP {
    const float *uf, *noise, *b_ue, *W_t, *b_t;
    const float *bias6[6];
    const float *Wn, *bn;
    const ushort *Wp;          // packed bf16 A-frag weights: 13 mats x 16384 ushorts
    float *out;
    float *pE, *pA0, *pU0, *pA1;   // per-block 128-f colsum partials
    unsigned *flg;
};
// Wp mat slots: 0,1 ca_aggr L0/L1; 2,3 ca_self; 4,5 ca_comb; 6,7 cu_aggr;
//               8,9 cu_self; 10,11 cu_comb; 12 W_ue

struct PrepP { const float* Wm[13]; ushort* Wp; unsigned* flg; };

// Wp[((m*4+kc)*8 + w)*512 + l*8 + j] = bf16( W[kc*32 + (l>>4)*8 + j][w*16 + (l&15)] )
// One thread per 8 output ushorts (uint4 store). 52 blocks x 512 = 13*16384/8.
// Blocks 0-31 additionally zero the 64 KB psync flag region (512 flags x 128B).
__global__ __launch_bounds__(512) void k_prep(PrepP Q)
{
    const int tid = threadIdx.x, blk = blockIdx.x;
    if (blk < 32) Q.flg[blk * 512 + tid] = 0;
    const int e = (blk * 512 + tid) * 8;
    const int l = (e >> 3) & 63, w = (e >> 9) & 7, kc = (e >> 12) & 3, m = e >> 14;
    const float* src = Q.Wm[m] + (kc * 32 + (l >> 4) * 8) * 128 + w * 16 + (l & 15);
    ushort h[8];
#pragma unroll
    for (int j = 0; j < 8; ++j) h[j] = f2bf(src[j * 128]);
    uint4 o = { (unsigned)h[0] | ((unsigned)h[1] << 16), (unsigned)h[2] | ((unsigned)h[3] << 16),
                (unsigned)h[4] | ((unsigned)h[5] << 16), (unsigned)h[6] | ((unsigned)h[7] << 16) };
    *(uint4*)(Q.Wp + e) = o;
}

// ---- 4-way sync: single-writer seq flags; wait on 3 same-XCD partners ----
__device__ __forceinline__ void psync4(unsigned* flg, int blk, unsigned s) {
    asm volatile("s_waitcnt vmcnt(0)" ::: "memory");   // drain my sc1 stores
    __syncthreads();
    if (threadIdx.x < 3) {
        if (threadIdx.x == 0)
            __hip_atomic_store(flg + blk * 32, s, __ATOMIC_RELAXED, SCOPE_AGT);
        unsigned* pf = flg + (((blk + 128 * (threadIdx.x + 1)) & 511) * 32);
        while (__hip_atomic_load(pf, __ATOMIC_RELAXED, SCOPE_AGT) < s)
            __builtin_amdgcn_s_sleep(1);
    }
    __syncthreads();
}

// ---- A-fragment fetch: 4 coalesced 16B loads from packed weights ----
struct AF { frag f[4]; };
__device__ __forceinline__ AF ldA(const ushort* __restrict__ Wp, int mat, int tid)
{
    AF a;
    const ushort* base = Wp + ((size_t)mat << 14) + (tid << 3);   // tid = wave*64+lane
#pragma unroll
    for (int kc = 0; kc < 4; ++kc)
        a.f[kc] = *(const frag*)(base + (kc << 12));
    return a;
}

// ---- MLP stage: wave w owns n-cols [16w,16w+16); one 16-row m-tile with
// VALID valid rows (8 for hu, 16 for ha). Rows >= VALID are stale in LDS and
// discarded (C-col m of the MFMA depends only on X-row m). CS: col-sum the
// stored values over valid rows -> csL (LDS) + csG (global, sc1).
template<int VALID, bool MEANADD, bool CS>
__device__ __forceinline__ void mlp_stage(const AF& A, const ushort* Xl, ushort* Yl,
    const float* biasL, const float* meanL, float* csL, float* __restrict__ csG,
    int n0, int l15, int q)
{
    const float4 bv = *(const float4*)(biasL + n0 + q * 4);
    float4 mv = {0.f, 0.f, 0.f, 0.f};
    if (MEANADD) mv = *(const float4*)(meanL + n0 + q * 4);
    frag Bv[4];
#pragma unroll
    for (int kc = 0; kc < 4; ++kc)
        Bv[kc] = *(const frag*)(Xl + l15 * LDST + kc * 32 + q * 8);
    f32x4 acc = {0.f, 0.f, 0.f, 0.f};
#pragma unroll
    for (int kc = 0; kc < 4; ++kc)
        acc = __builtin_amdgcn_mfma_f32_16x16x32_bf16(A.f[kc], Bv[kc], acc, 0, 0, 0);
    float v0 = acc[0] + bv.x, v1 = acc[1] + bv.y, v2 = acc[2] + bv.z, v3 = acc[3] + bv.w;
    v0 = v0 > 0.f ? v0 : 0.f; v1 = v1 > 0.f ? v1 : 0.f;
    v2 = v2 > 0.f ? v2 : 0.f; v3 = v3 > 0.f ? v3 : 0.f;
    if (MEANADD) { v0 += mv.x; v1 += mv.y; v2 += mv.z; v3 += mv.w; }
    const bool vr = (VALID == 16) || (l15 < VALID);
    if (vr) {
        uint2 o = { cvtpk(v0, v1), cvtpk(v2, v3) };
        *(uint2*)(Yl + l15 * LDST + n0 + q * 4) = o;
    }
    if (CS) {
        float cs0 = vr ? v0 : 0.f, cs1 = vr ? v1 : 0.f,
              cs2 = vr ? v2 : 0.f, cs3 = vr ? v3 : 0.f;
#pragma unroll
        for (int m = 1; m <= 8; m <<= 1) {
            cs0 += __shfl_xor(cs0, m); cs1 += __shfl_xor(cs1, m);
            cs2 += __shfl_xor(cs2, m); cs3 += __shfl_xor(cs3, m);
        }
        if (l15 == 0) {
            f32x4 t = { cs0, cs1, cs2, cs3 };
            *(f32x4*)(csL + n0 + q * 4) = t;
            gst16_sc(csG + n0 + q * 4, t);
        }
    }
}

__global__ __launch_bounds__(512, 4) void k_gnn(GP P)
{
    __shared__ __align__(16) ushort HU[16 * LDST];   // 8 valid hu rows
    __shared__ __align__(16) ushort HA[16 * LDST];   // 16 ha rows
    __shared__ __align__(16) ushort T0[16 * LDST];
    __shared__ __align__(16) ushort T1[16 * LDST];
    __shared__ __align__(16) float  biasL[1792];     // all bias vectors
    __shared__ __align__(16) float  redL[512];
    __shared__ __align__(16) float  WnS[2048];       // final Wn staging (8 KB)
    __shared__ __align__(16) float  meanP[128], meanQ[128], antL[128];

    const int blk = blockIdx.x, tid = threadIdx.x;
    const int b = blk & 127, qt = blk >> 7;          // batch, quarter
    const int p1 = (blk + 128) & 511, p2 = (blk + 256) & 511, p3 = (blk + 384) & 511;
    const int lane = tid & 63, wave = tid >> 6;
    const int q = lane >> 4, l15 = lane & 15;
    const int n0 = wave * 16;

    // ---- first A fetch (embed weights), then stage inputs ----
    AF An = ldA(P.Wp, 12, tid);

    if (tid < 256) {   // 8 uf rows -> T0 (256 float4 chunks)
        const int r = tid >> 5, k4 = tid & 31;
        const float4 v = *(const float4*)(P.uf + (size_t)(b * 32 + qt * 8 + r) * 128 + k4 * 4);
        uint2 o = { cvtpk(v.x, v.y), cvtpk(v.z, v.w) };
        *(uint2*)(T0 + r * LDST + k4 * 4) = o;
    }
    {   // 16 noise rows -> HA (512 chunks exactly; ant added later)
        const int r = tid >> 5, k4 = tid & 31;
        const float4 v = *(const float4*)(P.noise + (size_t)(b * 64 + qt * 16 + r) * 128 + k4 * 4);
        uint2 o = { cvtpk(v.x, v.y), cvtpk(v.z, v.w) };
        *(uint2*)(HA + r * LDST + k4 * 4) = o;
    }
    // bias vectors -> LDS (once)
    if (tid < 128) biasL[tid] = P.b_ue[tid];
    if (tid < 128) biasL[1664 + tid] = P.b_t[tid];
#pragma unroll
    for (int r = 0; r < 6; ++r)
        if (tid < 256) biasL[128 + r * 256 + tid] = P.bias6[r][tid];
    __syncthreads();

    AF A;
    // S1 embed: T0 -> HU (+fused E colsum)
    A = An; An = ldA(P.Wp, 0, tid);
    mlp_stage<8, false, true>(A, T0, HU, biasL + 0, nullptr, meanP, P.pE + blk * 128, n0, l15, q);
    __syncthreads();
    // S2-S3 it0 aggr-hu (+fused A0 colsum on S3)
    A = An; An = ldA(P.Wp, 1, tid);
    mlp_stage<8, false, false>(A, HU, T0, biasL + 128, nullptr, nullptr, nullptr, n0, l15, q);
    __syncthreads();
    A = An; An = ldA(P.Wp, 6, tid);
    mlp_stage<8, false, true>(A, T0, T1, biasL + 256, nullptr, meanQ, P.pA0 + blk * 128, n0, l15, q);
    __syncthreads();
    psync4(P.flg, blk, 1u);

    // ant = relu(meanE @ W_t + b_t); HA += ant ; combine meanQ (A0) too
    if (tid < 128) {
        meanP[tid] = (meanP[tid] + P.pE[p1 * 128 + tid] + P.pE[p2 * 128 + tid]
                                 + P.pE[p3 * 128 + tid]) * (1.f / 32.f);
        meanQ[tid] = (meanQ[tid] + P.pA0[p1 * 128 + tid] + P.pA0[p2 * 128 + tid]
                                 + P.pA0[p3 * 128 + tid]) * (1.f / 32.f);
    }
    __syncthreads();
    {
        const int g = tid >> 7, col = tid & 127;
        float s = 0.f;
#pragma unroll 4
        for (int k = g * 32; k < g * 32 + 32; ++k) s += meanP[k] * P.W_t[k * 128 + col];
        redL[g * 128 + col] = s;
    }
    __syncthreads();
    if (tid < 128) {
        float a = biasL[1664 + tid] + redL[tid] + redL[128 + tid] + redL[256 + tid] + redL[384 + tid];
        antL[tid] = a > 0.f ? a : 0.f;
    }
    __syncthreads();
    {   // HA += ant (512 chunks exactly)
        const int r = tid >> 5, k4 = tid & 31;
        ushort4 h = *(ushort4*)(HA + r * LDST + k4 * 4);
        uint2 o = { cvtpk(bf2f(h.x) + antL[k4 * 4 + 0], bf2f(h.y) + antL[k4 * 4 + 1]),
                    cvtpk(bf2f(h.z) + antL[k4 * 4 + 2], bf2f(h.w) + antL[k4 * 4 + 3]) };
        *(uint2*)(HA + r * LDST + k4 * 4) = o;
    }
    __syncthreads();

    // S4-S5 it0 aggr-ha (+fused U0 colsum on S5)
    A = An; An = ldA(P.Wp, 7, tid);
    mlp_stage<16, false, false>(A, HA, T0, biasL + 896, nullptr, nullptr, nullptr, n0, l15, q);
    __syncthreads();
    A = An; An = ldA(P.Wp, 2, tid);
    mlp_stage<16, false, true>(A, T0, T1, biasL + 1024, nullptr, meanP, P.pU0 + blk * 128, n0, l15, q);
    __syncthreads();
    // S6 self-ha L0 (independent of partners -> overlap psync2)
    A = An; An = ldA(P.Wp, 3, tid);
    mlp_stage<16, false, false>(A, HA, T0, biasL + 384, nullptr, nullptr, nullptr, n0, l15, q);
    __syncthreads();
    psync4(P.flg, blk, 2u);
    if (tid < 128)
        meanP[tid] = (meanP[tid] + P.pU0[p1 * 128 + tid] + P.pU0[p2 * 128 + tid]
                                 + P.pU0[p3 * 128 + tid]) * (1.f / 64.f);
    __syncthreads();
    // S7-S9 it0 comb-ha ; HA := ha2
    A = An; An = ldA(P.Wp, 4, tid);
    mlp_stage<16, true , false>(A, T0, T1, biasL + 512, meanQ, nullptr, nullptr, n0, l15, q);
    __syncthreads();
    A = An; An = ldA(P.Wp, 5, tid);
    mlp_stage<16, false, false>(A, T1, T0, biasL + 640, nullptr, nullptr, nullptr, n0, l15, q);
    __syncthreads();
    A = An; An = ldA(P.Wp, 8, tid);
    mlp_stage<16, false, false>(A, T0, HA, biasL + 768, nullptr, nullptr, nullptr, n0, l15, q);
    __syncthreads();
    // S10-S13 it0 comb-hu ; HU := hu2
    A = An; An = ldA(P.Wp, 9, tid);
    mlp_stage<8, false, false>(A, HU, T0, biasL + 1152, nullptr, nullptr, nullptr, n0, l15, q);
    __syncthreads();
    A = An; An = ldA(P.Wp, 10, tid);
    mlp_stage<8, true , false>(A, T0, T1, biasL + 1280, meanP, nullptr, nullptr, n0, l15, q);
    __syncthreads();
    A = An; An = ldA(P.Wp, 11, tid);
    mlp_stage<8, false, false>(A, T1, T0, biasL + 1408, nullptr, nullptr, nullptr, n0, l15, q);
    __syncthreads();
    A = An; An = ldA(P.Wp, 0, tid);
    mlp_stage<8, false, false>(A, T0, HU, biasL + 1536, nullptr, nullptr, nullptr, n0, l15, q);
    __syncthreads();

    // S14-S15 it1 aggr-hu2 (+fused A1 colsum on S15; it1 cu-side is dead)
    A = An; An = ldA(P.Wp, 1, tid);
    mlp_stage<8, false, false>(A, HU, T0, biasL + 128, nullptr, nullptr, nullptr, n0, l15, q);
    __syncthreads();
    A = An; An = ldA(P.Wp, 2, tid);
    mlp_stage<8, false, true>(A, T0, T1, biasL + 256, nullptr, meanQ, P.pA1 + blk * 128, n0, l15, q);
    __syncthreads();
    // S16 self-ha2 L0 (overlap psync3)
    A = An; An = ldA(P.Wp, 3, tid);
    mlp_stage<16, false, false>(A, HA, T0, biasL + 384, nullptr, nullptr, nullptr, n0, l15, q);
    __syncthreads();
    psync4(P.flg, blk, 3u);
    if (tid < 128)
        meanQ[tid] = (meanQ[tid] + P.pA1[p1 * 128 + tid] + P.pA1[p2 * 128 + tid]
                                 + P.pA1[p3 * 128 + tid]) * (1.f / 32.f);
    __syncthreads();
    // S17-S19 it1 comb-ha2 -> T1   (chain 3 -> 4 -> 5)
    A = An; An = ldA(P.Wp, 4, tid);
    mlp_stage<16, true , false>(A, T0, T1, biasL + 512, meanQ, nullptr, nullptr, n0, l15, q);
    __syncthreads();
    A = An; An = ldA(P.Wp, 5, tid);
    mlp_stage<16, false, false>(A, T1, T0, biasL + 640, nullptr, nullptr, nullptr, n0, l15, q);
    __syncthreads();
    A = An;
    mlp_stage<16, false, false>(A, T0, T1, biasL + 768, nullptr, nullptr, nullptr, n0, l15, q);
    __syncthreads();

    // ---- final: out = normalize(T1 @ Wn + bn); 16 rows x 16 cols = 256 ----
    // (vectorized: 16 x ds_read_b128 per thread)
    *(float4*)(WnS + tid * 4) = *(const float4*)(P.Wn + tid * 4);
    __syncthreads();
    if (tid < 256) {
        const int row = tid >> 4, j = tid & 15;
        float acc = P.bn[j];
        const uint4* h4 = (const uint4*)(T1 + row * LDST);
#pragma unroll
        for (int kb = 0; kb < 16; ++kb) {
            const uint4 u = h4[kb];
            const float* wp = WnS + kb * 128 + j;
            acc += bf2f((ushort)u.x) * wp[0]   + bf2f((ushort)(u.x >> 16)) * wp[16]
                 + bf2f((ushort)u.y) * wp[32]  + bf2f((ushort)(u.y >> 16)) * wp[48]
                 + bf2f((ushort)u.z) * wp[64]  + bf2f((ushort)(u.z >> 16)) * wp[80]
                 + bf2f((ushort)u.w) * wp[96]  + bf2f((ushort)(u.w >> 16)) * wp[112];
        }
        const float other = __shfl_xor(acc, 8);            // re<->im partner, same wave
        const float mag = sqrtf(acc * acc + other * other);
        P.out[(size_t)(b * 64 + qt * 16 + row) * 16 + j] = acc / mag;
    }
}

extern "C" void kernel_launch(void* const* d_in, const int* in_sizes, int n_in,
                              void* d_out, int out_size, void* d_ws, size_t ws_size,
                              hipStream_t stream)
{
    GP P;
    P.uf    = (const float*)d_in[0];
    P.noise = (const float*)d_in[1];
    const float* W_ue = (const float*)d_in[6];
    P.b_ue  = (const float*)d_in[7];
    P.W_t   = (const float*)d_in[8];
    P.b_t   = (const float*)d_in[9];
    const float* caW[3] = {(const float*)d_in[10], (const float*)d_in[12], (const float*)d_in[14]};
    const float* cab[3] = {(const float*)d_in[11], (const float*)d_in[13], (const float*)d_in[15]};
    const float* cuW[3] = {(const float*)d_in[16], (const float*)d_in[18], (const float*)d_in[20]};
    const float* cub[3] = {(const float*)d_in[17], (const float*)d_in[19], (const float*)d_in[21]};
    P.Wn  = (const float*)d_in[22];
    P.bn  = (const float*)d_in[23];
    P.out = (float*)d_out;

    PrepP Q;
    Q.Wm[0]  = caW[0]; Q.Wm[1]  = caW[0] + 16384;
    Q.Wm[2]  = caW[1]; Q.Wm[3]  = caW[1] + 16384;
    Q.Wm[4]  = caW[2]; Q.Wm[5]  = caW[2] + 16384;
    Q.Wm[6]  = cuW[0]; Q.Wm[7]  = cuW[0] + 16384;
    Q.Wm[8]  = cuW[1]; Q.Wm[9]  = cuW[1] + 16384;
    Q.Wm[10] = cuW[2]; Q.Wm[11] = cuW[2] + 16384;
    Q.Wm[12] = W_ue;
    P.bias6[0] = cab[0]; P.bias6[1] = cab[1]; P.bias6[2] = cab[2];
    P.bias6[3] = cub[0]; P.bias6[4] = cub[1]; P.bias6[5] = cub[2];

    char* w = (char*)d_ws;
    P.flg = (unsigned*)w;                       // 512 flags, 128 B apart (64 KB)
    P.pE  = (float*)(w + 65536);                // 4 partial arrays, 512*128 f each (1 MB)
    P.pA0 = P.pE  + 512 * 128;
    P.pU0 = P.pA0 + 512 * 128;
    P.pA1 = P.pU0 + 512 * 128;
    ushort* Wp = (ushort*)(w + 65536 + 4 * 512 * 128 * 4);   // 13 * 32 KB packed weights
    Q.Wp = Wp;
    Q.flg = P.flg;
    P.Wp = Wp;

    k_prep<<<dim3(52), dim3(512), 0, stream>>>(Q);   // also zeroes flags
    k_gnn<<<dim3(512), dim3(512), 0, stream>>>(P);
}

// Round 18
// 120.396 us; speedup vs baseline: 1.0532x; 1.0532x over previous
//
#include <hip/hip_runtime.h>
#include <math.h>

// B=128, NU=32, NT=64, H=128, OUT_F=16, N_U=4096, N_A=8192
// Per-batch-local GNN. R21 == R20 == R15 (verified best, 120.76 us),
// resubmitted after round-17 container failure (infra, not kernel).
// Structural bracket measured:
//   R14 full-batch  (128x1024, 2x per-CU work): 123.8 (+3.1)
//   R15 half-batch  (256x512,  1 blk/CU):       120.76  <== best
//   R16 quarter-batch (512x512, 2 blk/CU):      126.8 (+6.0)
// R15 is a measured local optimum in both structural directions. ~81 us of
// the 120.76 is two immovable 256MiB harness poison fills (~82% HBM peak);
// the ~40 us controllable slice is a latency-bound 22-stage barrier chain
// whose remaining levers are sub-us.
//   Structure: 256 blocks x 512 threads (8 waves, n-split 8); block (b,half)
//   owns 16 hu + 32 ha rows in LDS end-to-end. Colsums fused into producing
//   mlp_stage (16-lane shuffle reduce, l15==0 writes LDS partial + sc1
//   global partial). Packed bf16 A-frag weights from prep kernel (also
//   zeroes flags), prefetched one stage ahead. Same-XCD psync pairing
//   (partner = blk ^ 128). Vectorized final normalize (16 x ds_read_b128).
// Workspace: 32KB flags + 512KB partials + 416KB packed weights.

using frag  = __attribute__((ext_vector_type(8))) short;   // 8 x bf16
using f32x4 = __attribute__((ext_vector_type(4))) float;

#define LDST 136
#define SCOPE_AGT __HIP_MEMORY_SCOPE_AGENT

__device__ __forceinline__ float  bf2f(ushort u) { return __uint_as_float(((unsigned)u) << 16); }
__device__ __forceinline__ ushort f2bf(float f) {
    unsigned u = __float_as_uint(f);
    u += 0x7fff + ((u >> 16) & 1);            // RNE
    return (ushort)(u >> 16);
}
__device__ __forceinline__ unsigned cvtpk(float lo, float hi) {   // [hi:lo] bf16 pair, RNE
    unsigned r;
    asm("v_cvt_pk_bf16_f32 %0, %1, %2" : "=v"(r) : "v"(lo), "v"(hi));
    return r;
}
__device__ __forceinline__ void gst16_sc(void* p, f32x4 v) {   // write-through to MALL
    asm volatile("global_store_dwordx4 %0, %1, off sc1" :: "v"(p), "v"(v) : "memory");
}

struct GP {
    const float *uf, *noise, *b_ue, *W_t, *b_t;
    const float *bias6[6];
    const float *Wn, *bn;
    const ushort *Wp;          // packed bf16 A-frag weights: 13 mats x 16384 ushorts
    float *out;
    float *pE, *pA0, *pU0, *pA1;   // per-block 128-f colsum partials
    unsigned *flg;
};
// Wp mat slots: 0,1 ca_aggr L0/L1; 2,3 ca_self; 4,5 ca_comb; 6,7 cu_aggr;
//               8,9 cu_self; 10,11 cu_comb; 12 W_ue

struct PrepP { const float* Wm[13]; ushort* Wp; unsigned* flg; };

// Wp[((m*4+kc)*8 + w)*512 + l*8 + j] = bf16( W[kc*32 + (l>>4)*8 + j][w*16 + (l&15)] )
// One thread per 8 output ushorts (uint4 store). 52 blocks x 512 = 13*16384/8.
// Blocks 0-15 additionally zero the 32 KB psync flag region.
__global__ __launch_bounds__(512) void k_prep(PrepP Q)
{
    const int tid = threadIdx.x, blk = blockIdx.x;
    if (blk < 16) Q.flg[blk * 512 + tid] = 0;
    const int e = (blk * 512 + tid) * 8;
    const int l = (e >> 3) & 63, w = (e >> 9) & 7, kc = (e >> 12) & 3, m = e >> 14;
    const float* src = Q.Wm[m] + (kc * 32 + (l >> 4) * 8) * 128 + w * 16 + (l & 15);
    ushort h[8];
#pragma unroll
    for (int j = 0; j < 8; ++j) h[j] = f2bf(src[j * 128]);
    uint4 o = { (unsigned)h[0] | ((unsigned)h[1] << 16), (unsigned)h[2] | ((unsigned)h[3] << 16),
                (unsigned)h[4] | ((unsigned)h[5] << 16), (unsigned)h[6] | ((unsigned)h[7] << 16) };
    *(uint4*)(Q.Wp + e) = o;
}

// ---- pairwise sync: single-writer seq flags ----
__device__ __forceinline__ void psync(unsigned* myf, unsigned* pf, unsigned s) {
    asm volatile("s_waitcnt vmcnt(0)" ::: "memory");   // drain my sc1 stores
    __syncthreads();
    if (threadIdx.x == 0) {
        __hip_atomic_store(myf, s, __ATOMIC_RELAXED, SCOPE_AGT);
        while (__hip_atomic_load(pf, __ATOMIC_RELAXED, SCOPE_AGT) < s)
            __builtin_amdgcn_s_sleep(1);
    }
    __syncthreads();
}

// ---- A-fragment fetch: 4 coalesced 16B loads from packed weights ----
struct AF { frag f[4]; };
__device__ __forceinline__ AF ldA(const ushort* __restrict__ Wp, int mat, int tid)
{
    AF a;
    const ushort* base = Wp + ((size_t)mat << 14) + (tid << 3);   // tid = wave*64+lane
#pragma unroll
    for (int kc = 0; kc < 4; ++kc)
        a.f[kc] = *(const frag*)(base + (kc << 12));
    return a;
}

// ---- MLP stage: wave w owns n-cols [16w,16w+16); MT m-tiles; LDS bias ----
// CS: additionally col-sum the stored (post-relu) values over all MT*16 rows,
// writing the wave's 16-col partial to csL (LDS) and csG (global, sc1).
template<int MT, bool MEANADD, bool CS>
__device__ __forceinline__ void mlp_stage(const AF& A, const ushort* Xl, ushort* Yl,
    const float* biasL, const float* meanL, float* csL, float* __restrict__ csG,
    int n0, int l15, int q)
{
    const float4 bv = *(const float4*)(biasL + n0 + q * 4);
    float4 mv = {0.f, 0.f, 0.f, 0.f};
    if (MEANADD) mv = *(const float4*)(meanL + n0 + q * 4);
    float cs0 = 0.f, cs1 = 0.f, cs2 = 0.f, cs3 = 0.f;
#pragma unroll
    for (int mt = 0; mt < MT; ++mt) {
        frag Bv[4];
#pragma unroll
        for (int kc = 0; kc < 4; ++kc)
            Bv[kc] = *(const frag*)(Xl + (mt * 16 + l15) * LDST + kc * 32 + q * 8);
        f32x4 acc = {0.f, 0.f, 0.f, 0.f};
#pragma unroll
        for (int kc = 0; kc < 4; ++kc)
            acc = __builtin_amdgcn_mfma_f32_16x16x32_bf16(A.f[kc], Bv[kc], acc, 0, 0, 0);
        float v0 = acc[0] + bv.x, v1 = acc[1] + bv.y, v2 = acc[2] + bv.z, v3 = acc[3] + bv.w;
        v0 = v0 > 0.f ? v0 : 0.f; v1 = v1 > 0.f ? v1 : 0.f;
        v2 = v2 > 0.f ? v2 : 0.f; v3 = v3 > 0.f ? v3 : 0.f;
        if (MEANADD) { v0 += mv.x; v1 += mv.y; v2 += mv.z; v3 += mv.w; }
        if (CS) { cs0 += v0; cs1 += v1; cs2 += v2; cs3 += v3; }
        uint2 o = { cvtpk(v0, v1), cvtpk(v2, v3) };
        *(uint2*)(Yl + (mt * 16 + l15) * LDST + n0 + q * 4) = o;
    }
    if (CS) {
        // reduce over the 16 l15 lanes of this q-group (cols are wave-exclusive)
#pragma unroll
        for (int m = 1; m <= 8; m <<= 1) {
            cs0 += __shfl_xor(cs0, m); cs1 += __shfl_xor(cs1, m);
            cs2 += __shfl_xor(cs2, m); cs3 += __shfl_xor(cs3, m);
        }
        if (l15 == 0) {
            f32x4 t = { cs0, cs1, cs2, cs3 };
            *(f32x4*)(csL + n0 + q * 4) = t;
            gst16_sc(csG + n0 + q * 4, t);
        }
    }
}

__global__ __launch_bounds__(512, 1) void k_gnn(GP P)
{
    __shared__ __align__(16) ushort HU[16 * LDST];   // hu -> (aliased) hu2
    __shared__ __align__(16) ushort HA[32 * LDST];   // ha -> (aliased) ha2
    __shared__ __align__(16) ushort T0[32 * LDST];
    __shared__ __align__(16) ushort T1[32 * LDST];
    __shared__ __align__(16) float  biasL[1792];     // all bias vectors
    __shared__ __align__(16) float  redL[512];
    __shared__ __align__(16) float  meanP[128], meanQ[128], antL[128];

    const int blk = blockIdx.x, tid = threadIdx.x;
    // same-XCD pairing: partner = blk ^ 128 (same XCD under round-robin %8)
    const int b = blk & 127, half = blk >> 7, prt = blk ^ 128;
    const int lane = tid & 63, wave = tid >> 6;
    const int q = lane >> 4, l15 = lane & 15;
    const int n0 = wave * 16;
    unsigned* myf = P.flg + blk * 32;
    unsigned* prf = P.flg + prt * 32;

    // ---- first A fetch (embed weights), then stage inputs ----
    AF An = ldA(P.Wp, 12, tid);

    {   // 16 uf rows -> T0 (512 float4 chunks exactly)
        const int r = tid >> 5, k4 = tid & 31;
        const float4 v = *(const float4*)(P.uf + (size_t)(b * 32 + half * 16 + r) * 128 + k4 * 4);
        uint2 o = { cvtpk(v.x, v.y), cvtpk(v.z, v.w) };
        *(uint2*)(T0 + r * LDST + k4 * 4) = o;
    }
#pragma unroll
    for (int c = tid; c < 1024; c += 512) {   // 32 noise rows -> HA (ant added later)
        const int r = c >> 5, k4 = c & 31;
        const float4 v = *(const float4*)(P.noise + (size_t)(b * 64 + half * 32 + r) * 128 + k4 * 4);
        uint2 o = { cvtpk(v.x, v.y), cvtpk(v.z, v.w) };
        *(uint2*)(HA + r * LDST + k4 * 4) = o;
    }
    // bias vectors -> LDS (once)
    if (tid < 128) biasL[tid] = P.b_ue[tid];
    if (tid < 128) biasL[1664 + tid] = P.b_t[tid];
#pragma unroll
    for (int r = 0; r < 6; ++r)
        if (tid < 256) biasL[128 + r * 256 + tid] = P.bias6[r][tid];
    __syncthreads();

    AF A;
    // S1 embed: T0 -> HU (+fused E colsum)
    A = An; An = ldA(P.Wp, 0, tid);
    mlp_stage<1, false, true>(A, T0, HU, biasL + 0, nullptr, meanP, P.pE + blk * 128, n0, l15, q);
    __syncthreads();
    // S2-S3 it0 aggr-hu (+fused A0 colsum on S3)
    A = An; An = ldA(P.Wp, 1, tid);
    mlp_stage<1, false, false>(A, HU, T0, biasL + 128, nullptr, nullptr, nullptr, n0, l15, q);
    __syncthreads();
    A = An; An = ldA(P.Wp, 6, tid);
    mlp_stage<1, false, true>(A, T0, T1, biasL + 256, nullptr, meanQ, P.pA0 + blk * 128, n0, l15, q);
    __syncthreads();
    psync(myf, prf, 1u);

    // ant = relu(meanE @ W_t + b_t); HA += ant ; combine meanQ (A0) too
    if (tid < 128) {
        meanP[tid] = (meanP[tid] + P.pE[prt * 128 + tid]) * (1.f / 32.f);
        meanQ[tid] = (meanQ[tid] + P.pA0[prt * 128 + tid]) * (1.f / 32.f);
    }
    __syncthreads();
    {
        const int g = tid >> 7, col = tid & 127;
        float s = 0.f;
#pragma unroll 4
        for (int k = g * 32; k < g * 32 + 32; ++k) s += meanP[k] * P.W_t[k * 128 + col];
        redL[g * 128 + col] = s;
    }
    __syncthreads();
    if (tid < 128) {
        float a = biasL[1664 + tid] + redL[tid] + redL[128 + tid] + redL[256 + tid] + redL[384 + tid];
        antL[tid] = a > 0.f ? a : 0.f;
    }
    __syncthreads();
#pragma unroll
    for (int c = tid; c < 1024; c += 512) {
        const int r = c >> 5, k4 = c & 31;
        ushort4 h = *(ushort4*)(HA + r * LDST + k4 * 4);
        uint2 o = { cvtpk(bf2f(h.x) + antL[k4 * 4 + 0], bf2f(h.y) + antL[k4 * 4 + 1]),
                    cvtpk(bf2f(h.z) + antL[k4 * 4 + 2], bf2f(h.w) + antL[k4 * 4 + 3]) };
        *(uint2*)(HA + r * LDST + k4 * 4) = o;
    }
    __syncthreads();

    // S4-S5 it0 aggr-ha (+fused U0 colsum on S5)
    A = An; An = ldA(P.Wp, 7, tid);
    mlp_stage<2, false, false>(A, HA, T0, biasL + 896, nullptr, nullptr, nullptr, n0, l15, q);
    __syncthreads();
    A = An; An = ldA(P.Wp, 2, tid);
    mlp_stage<2, false, true>(A, T0, T1, biasL + 1024, nullptr, meanP, P.pU0 + blk * 128, n0, l15, q);
    __syncthreads();
    // S6 self-ha L0 (independent of partner -> overlap psync2)
    A = An; An = ldA(P.Wp, 3, tid);
    mlp_stage<2, false, false>(A, HA, T0, biasL + 384, nullptr, nullptr, nullptr, n0, l15, q);
    __syncthreads();
    psync(myf, prf, 2u);
    if (tid < 128)
        meanP[tid] = (meanP[tid] + P.pU0[prt * 128 + tid]) * (1.f / 64.f);
    __syncthreads();
    // S7-S9 it0 comb-ha ; HA := ha2
    A = An; An = ldA(P.Wp, 4, tid);
    mlp_stage<2, true , false>(A, T0, T1, biasL + 512, meanQ, nullptr, nullptr, n0, l15, q);
    __syncthreads();
    A = An; An = ldA(P.Wp, 5, tid);
    mlp_stage<2, false, false>(A, T1, T0, biasL + 640, nullptr, nullptr, nullptr, n0, l15, q);
    __syncthreads();
    A = An; An = ldA(P.Wp, 8, tid);
    mlp_stage<2, false, false>(A, T0, HA, biasL + 768, nullptr, nullptr, nullptr, n0, l15, q);
    __syncthreads();
    // S10-S13 it0 comb-hu ; HU := hu2
    A = An; An = ldA(P.Wp, 9, tid);
    mlp_stage<1, false, false>(A, HU, T0, biasL + 1152, nullptr, nullptr, nullptr, n0, l15, q);
    __syncthreads();
    A = An; An = ldA(P.Wp, 10, tid);
    mlp_stage<1, true , false>(A, T0, T1, biasL + 1280, meanP, nullptr, nullptr, n0, l15, q);
    __syncthreads();
    A = An; An = ldA(P.Wp, 11, tid);
    mlp_stage<1, false, false>(A, T1, T0, biasL + 1408, nullptr, nullptr, nullptr, n0, l15, q);
    __syncthreads();
    A = An; An = ldA(P.Wp, 0, tid);
    mlp_stage<1, false, false>(A, T0, HU, biasL + 1536, nullptr, nullptr, nullptr, n0, l15, q);
    __syncthreads();

    // S14-S15 it1 aggr-hu2 (+fused A1 colsum on S15; it1 cu-side is dead)
    A = An; An = ldA(P.Wp, 1, tid);
    mlp_stage<1, false, false>(A, HU, T0, biasL + 128, nullptr, nullptr, nullptr, n0, l15, q);
    __syncthreads();
    A = An; An = ldA(P.Wp, 2, tid);
    mlp_stage<1, false, true>(A, T0, T1, biasL + 256, nullptr, meanQ, P.pA1 + blk * 128, n0, l15, q);
    __syncthreads();
    // S16 self-ha2 L0 (overlap psync3)
    A = An; An = ldA(P.Wp, 3, tid);
    mlp_stage<2, false, false>(A, HA, T0, biasL + 384, nullptr, nullptr, nullptr, n0, l15, q);
    __syncthreads();
    psync(myf, prf, 3u);
    if (tid < 128)
        meanQ[tid] = (meanQ[tid] + P.pA1[prt * 128 + tid]) * (1.f / 32.f);
    __syncthreads();
    // S17-S19 it1 comb-ha2 -> T1   (chain 3 -> 4 -> 5)
    A = An; An = ldA(P.Wp, 4, tid);
    mlp_stage<2, true , false>(A, T0, T1, biasL + 512, meanQ, nullptr, nullptr, n0, l15, q);
    __syncthreads();
    A = An; An = ldA(P.Wp, 5, tid);
    mlp_stage<2, false, false>(A, T1, T0, biasL + 640, nullptr, nullptr, nullptr, n0, l15, q);
    __syncthreads();
    A = An;
    mlp_stage<2, false, false>(A, T0, T1, biasL + 768, nullptr, nullptr, nullptr, n0, l15, q);
    __syncthreads();

    // ---- final: out = normalize(T1 @ Wn + bn); 32 rows x 16 cols = 512 ----
    // (vectorized: 16 x ds_read_b128 per thread instead of 128 scalar u16)
    float* WnS = (float*)T0;                               // 8 KB <= T0
    *(float4*)(WnS + tid * 4) = *(const float4*)(P.Wn + tid * 4);
    __syncthreads();
    {
        const int row = tid >> 4, j = tid & 15;
        float acc = P.bn[j];
        const uint4* h4 = (const uint4*)(T1 + row * LDST);
#pragma unroll
        for (int kb = 0; kb < 16; ++kb) {
            const uint4 u = h4[kb];
            const float* wp = WnS + kb * 128 + j;
            acc += bf2f((ushort)u.x) * wp[0]   + bf2f((ushort)(u.x >> 16)) * wp[16]
                 + bf2f((ushort)u.y) * wp[32]  + bf2f((ushort)(u.y >> 16)) * wp[48]
                 + bf2f((ushort)u.z) * wp[64]  + bf2f((ushort)(u.z >> 16)) * wp[80]
                 + bf2f((ushort)u.w) * wp[96]  + bf2f((ushort)(u.w >> 16)) * wp[112];
        }
        const float other = __shfl_xor(acc, 8);            // re<->im partner, same wave
        const float mag = sqrtf(acc * acc + other * other);
        P.out[(size_t)(b * 64 + half * 32 + row) * 16 + j] = acc / mag;
    }
}

extern "C" void kernel_launch(void* const* d_in, const int* in_sizes, int n_in,
                              void* d_out, int out_size, void* d_ws, size_t ws_size,
                              hipStream_t stream)
{
    GP P;
    P.uf    = (const float*)d_in[0];
    P.noise = (const float*)d_in[1];
    const float* W_ue = (const float*)d_in[6];
    P.b_ue  = (const float*)d_in[7];
    P.W_t   = (const float*)d_in[8];
    P.b_t   = (const float*)d_in[9];
    const float* caW[3] = {(const float*)d_in[10], (const float*)d_in[12], (const float*)d_in[14]};
    const float* cab[3] = {(const float*)d_in[11], (const float*)d_in[13], (const float*)d_in[15]};
    const float* cuW[3] = {(const float*)d_in[16], (const float*)d_in[18], (const float*)d_in[20]};
    const float* cub[3] = {(const float*)d_in[17], (const float*)d_in[19], (const float*)d_in[21]};
    P.Wn  = (const float*)d_in[22];
    P.bn  = (const float*)d_in[23];
    P.out = (float*)d_out;

    PrepP Q;
    Q.Wm[0]  = caW[0]; Q.Wm[1]  = caW[0] + 16384;
    Q.Wm[2]  = caW[1]; Q.Wm[3]  = caW[1] + 16384;
    Q.Wm[4]  = caW[2]; Q.Wm[5]  = caW[2] + 16384;
    Q.Wm[6]  = cuW[0]; Q.Wm[7]  = cuW[0] + 16384;
    Q.Wm[8]  = cuW[1]; Q.Wm[9]  = cuW[1] + 16384;
    Q.Wm[10] = cuW[2]; Q.Wm[11] = cuW[2] + 16384;
    Q.Wm[12] = W_ue;
    P.bias6[0] = cab[0]; P.bias6[1] = cab[1]; P.bias6[2] = cab[2];
    P.bias6[3] = cub[0]; P.bias6[4] = cub[1]; P.bias6[5] = cub[2];

    char* w = (char*)d_ws;
    P.flg = (unsigned*)w;                       // 256 flags, 128 B apart (32 KB)
    P.pE  = (float*)(w + 32768);                // 4 partial arrays, 256*128 f each
    P.pA0 = P.pE  + 256 * 128;
    P.pU0 = P.pA0 + 256 * 128;
    P.pA1 = P.pU0 + 256 * 128;
    ushort* Wp = (ushort*)(w + 32768 + 4 * 256 * 128 * 4);   // 13 * 32 KB packed weights
    Q.Wp = Wp;
    Q.flg = P.flg;
    P.Wp = Wp;

    k_prep<<<dim3(52), dim3(512), 0, stream>>>(Q);   // also zeroes flags
    k_gnn<<<dim3(256), dim3(512), 0, stream>>>(P);
}